// Round 1
// baseline (1119.100 us; speedup 1.0000x reference)
//
#include <hip/hip_runtime.h>
#include <math.h>

// ---------------------------------------------------------------------------
// Top2Router: softmax -> top2 experts -> ordered capacity ranks -> dense
// [s, e, cap] combine-weight + mask output (1.07 GB, store-bound).
// ---------------------------------------------------------------------------

#define NEXPERTS 64

__device__ __forceinline__ float wave_max64(float v) {
    #pragma unroll
    for (int d = 32; d >= 1; d >>= 1) v = fmaxf(v, __shfl_xor(v, d, 64));
    return v;
}
__device__ __forceinline__ float wave_sum64(float v) {
    #pragma unroll
    for (int d = 32; d >= 1; d >>= 1) v += __shfl_xor(v, d, 64);
    return v;
}
// argmax across 64 lanes, first-index tie-break (matches jnp.argmax)
__device__ __forceinline__ int wave_argmax64(float v, int lane) {
    int i = lane;
    #pragma unroll
    for (int d = 32; d >= 1; d >>= 1) {
        float ov = __shfl_xor(v, d, 64);
        int   oi = __shfl_xor(i, d, 64);
        if (ov > v || (ov == v && oi < i)) { v = ov; i = oi; }
    }
    return i;  // wave-uniform
}

// K1: one wave per token: fp32 softmax, top1/top2 index + prob.
__global__ void __launch_bounds__(256) k_softmax_top2(
    const float* __restrict__ in, int s,
    int* __restrict__ top1, int* __restrict__ top2,
    float* __restrict__ w1, float* __restrict__ w2) {
    int wave = threadIdx.x >> 6;
    int lane = threadIdx.x & 63;
    int i = blockIdx.x * (blockDim.x >> 6) + wave;
    if (i >= s) return;

    float x = in[(size_t)i * NEXPERTS + lane];
    float m = wave_max64(x);
    float p = expf(x - m);
    float sum = wave_sum64(p);
    float prob = p / sum;

    int e1 = wave_argmax64(x, lane);
    float x2 = (lane == e1) ? -INFINITY : x;
    int e2 = wave_argmax64(x2, lane);

    float p1 = __shfl(prob, e1, 64);
    float p2 = __shfl(prob, e2, 64);
    if (lane == 0) {
        top1[i] = e1; top2[i] = e2; w1[i] = p1; w2[i] = p2;
    }
}

// K2: single block, 16 waves. Ordered exclusive prefix counts per expert.
// rank1[i] = #{j<i : top1_j == top1_i}
// rank2[i] = #{j<i : top2_j == top2_i} + total_count(top1 == top2_i)
__global__ void __launch_bounds__(1024) k_ranks(
    const int* __restrict__ top1, const int* __restrict__ top2, int s,
    int* __restrict__ rank1, int* __restrict__ rank2) {
    __shared__ unsigned short lr1[8192];
    __shared__ unsigned short lr2[8192];
    __shared__ int hist1[16][NEXPERTS];
    __shared__ int hist2[16][NEXPERTS];
    __shared__ int off1[16][NEXPERTS];
    __shared__ int off2[16][NEXPERTS];

    int tid = threadIdx.x;
    int w = tid >> 6;          // wave id: chunk owner
    int lane = tid & 63;       // lane == expert id in pass 1
    int chunk = (s + 15) >> 4; // 512 for s=8192
    int beg = w * chunk;
    int end = min(beg + chunk, s);

    // pass 1: per-chunk ordered local ranks (lane e counts expert e)
    int cnt1 = 0, cnt2 = 0;
    for (int base = beg; base < end; base += 64) {
        int n = min(64, end - base);
        int t1 = 0, t2 = 0;
        if (lane < n) { t1 = top1[base + lane]; t2 = top2[base + lane]; }
        for (int k = 0; k < n; ++k) {
            int i1 = __shfl(t1, k, 64);
            int i2 = __shfl(t2, k, 64);
            if (lane == i1) lr1[base + k] = (unsigned short)cnt1;
            cnt1 += (lane == i1) ? 1 : 0;
            if (lane == i2) lr2[base + k] = (unsigned short)cnt2;
            cnt2 += (lane == i2) ? 1 : 0;
        }
    }
    hist1[w][lane] = cnt1;
    hist2[w][lane] = cnt2;
    __syncthreads();

    // pass 2: exclusive scan of chunk histograms per expert (+ total top1)
    {
        int o1 = 0, o2 = 0, tot1 = 0;
        #pragma unroll
        for (int k = 0; k < 16; ++k) {
            int h1 = hist1[k][lane], h2 = hist2[k][lane];
            if (k < w) { o1 += h1; o2 += h2; }
            tot1 += h1;
        }
        off1[w][lane] = o1;
        off2[w][lane] = tot1 + o2;  // rank2 offset includes full top1 count
    }
    __syncthreads();

    // pass 3: final ranks to global
    for (int i = tid; i < s; i += 1024) {
        int c = i / chunk;
        rank1[i] = (int)lr1[i] + off1[c][top1[i]];
        rank2[i] = (int)lr2[i] + off2[c][top2[i]];
    }
}

// K3: one block per token; write the full [64, cap] weight row and mask row.
// At most 2 nonzero flat slots per row (n1, n2); everything else 0.
__global__ void __launch_bounds__(256) k_fill(
    const int* __restrict__ top1, const int* __restrict__ top2,
    const float* __restrict__ w1, const float* __restrict__ w2,
    const int* __restrict__ rank1, const int* __restrict__ rank2,
    int capacity, float* __restrict__ out, size_t mask_off) {
    int i = blockIdx.x;
    int e1 = top1[i], e2 = top2[i];
    int r1 = rank1[i], r2 = rank2[i];
    float p1 = w1[i], p2 = w2[i];

    int ec = NEXPERTS * capacity;                       // 16384 floats/row
    int n1 = (r1 < capacity) ? (e1 * capacity + r1) : -1;
    int n2 = (r2 < capacity) ? (e2 * capacity + r2) : -1;

    float4* ow = (float4*)(out + (size_t)i * ec);
    float4* om = (float4*)(out + mask_off + (size_t)i * ec);
    int nf4 = ec >> 2;                                  // 4096 float4/row
    for (int j = threadIdx.x; j < nf4; j += blockDim.x) {
        int f = j << 2;
        float4 v;
        v.x = (f + 0 == n1) ? p1 : ((f + 0 == n2) ? p2 : 0.0f);
        v.y = (f + 1 == n1) ? p1 : ((f + 1 == n2) ? p2 : 0.0f);
        v.z = (f + 2 == n1) ? p1 : ((f + 2 == n2) ? p2 : 0.0f);
        v.w = (f + 3 == n1) ? p1 : ((f + 3 == n2) ? p2 : 0.0f);
        float4 mk;
        mk.x = (v.x != 0.0f) ? 1.0f : 0.0f;
        mk.y = (v.y != 0.0f) ? 1.0f : 0.0f;
        mk.z = (v.z != 0.0f) ? 1.0f : 0.0f;
        mk.w = (v.w != 0.0f) ? 1.0f : 0.0f;
        ow[j] = v;
        om[j] = mk;
    }
}

extern "C" void kernel_launch(void* const* d_in, const int* in_sizes, int n_in,
                              void* d_out, int out_size, void* d_ws, size_t ws_size,
                              hipStream_t stream) {
    const float* in = (const float*)d_in[0];
    int s = in_sizes[0] / NEXPERTS;          // 8192

    // capacity = max(floor(2.0*s/e) rounded up to even, 4)
    int cap = (int)(2.0 * s / NEXPERTS);
    cap += cap % 2;
    if (cap < 4) cap = 4;                    // = 256 here

    int*   top1  = (int*)d_ws;
    int*   top2  = top1 + s;
    int*   rank1 = top2 + s;
    int*   rank2 = rank1 + s;
    float* w1    = (float*)(rank2 + s);
    float* w2    = w1 + s;

    float* out = (float*)d_out;
    size_t mask_off = (size_t)s * NEXPERTS * cap;   // second output (mask)

    int tokensPerBlock = 4;  // 4 waves of 64
    int b1 = (s + tokensPerBlock - 1) / tokensPerBlock;
    k_softmax_top2<<<b1, 256, 0, stream>>>(in, s, top1, top2, w1, w2);
    k_ranks<<<1, 1024, 0, stream>>>(top1, top2, s, rank1, rank2);
    k_fill<<<s, 256, 0, stream>>>(top1, top2, w1, w2, rank1, rank2, cap, out, mask_off);
}

// Round 2
// 1118.616 us; speedup vs baseline: 1.0004x; 1.0004x over previous
//
#include <hip/hip_runtime.h>
#include <math.h>

// ---------------------------------------------------------------------------
// Top2Router: softmax -> top2 experts -> ordered capacity ranks -> dense
// [s, e, cap] combine-weight + mask output.
// Output is 2.147 GB, >99.99% zeros: zero it with hipMemsetAsync (rides the
// runtime fill path measured at 6.2 TB/s) and scatter the <=4 nonzero dwords
// per token from the ranks kernel.
// ---------------------------------------------------------------------------

#define NEXPERTS 64

__device__ __forceinline__ float wave_max64(float v) {
    #pragma unroll
    for (int d = 32; d >= 1; d >>= 1) v = fmaxf(v, __shfl_xor(v, d, 64));
    return v;
}
__device__ __forceinline__ float wave_sum64(float v) {
    #pragma unroll
    for (int d = 32; d >= 1; d >>= 1) v += __shfl_xor(v, d, 64);
    return v;
}
// argmax across 64 lanes, first-index tie-break (matches jnp.argmax)
__device__ __forceinline__ int wave_argmax64(float v, int lane) {
    int i = lane;
    #pragma unroll
    for (int d = 32; d >= 1; d >>= 1) {
        float ov = __shfl_xor(v, d, 64);
        int   oi = __shfl_xor(i, d, 64);
        if (ov > v || (ov == v && oi < i)) { v = ov; i = oi; }
    }
    return i;  // wave-uniform
}

// K1: one wave per token: fp32 softmax, top1/top2 index + prob.
__global__ void __launch_bounds__(256) k_softmax_top2(
    const float* __restrict__ in, int s,
    int* __restrict__ top1, int* __restrict__ top2,
    float* __restrict__ w1, float* __restrict__ w2) {
    int wave = threadIdx.x >> 6;
    int lane = threadIdx.x & 63;
    int i = blockIdx.x * (blockDim.x >> 6) + wave;
    if (i >= s) return;

    float x = in[(size_t)i * NEXPERTS + lane];
    float m = wave_max64(x);
    float p = expf(x - m);
    float sum = wave_sum64(p);
    float prob = p / sum;

    int e1 = wave_argmax64(x, lane);
    float x2 = (lane == e1) ? -INFINITY : x;
    int e2 = wave_argmax64(x2, lane);

    float p1 = __shfl(prob, e1, 64);
    float p2 = __shfl(prob, e2, 64);
    if (lane == 0) {
        top1[i] = e1; top2[i] = e2; w1[i] = p1; w2[i] = p2;
    }
}

// K2: single block, 16 waves. Ordered exclusive prefix counts per expert,
// then scatter the nonzero weight/mask dwords directly into the (pre-zeroed)
// dense output.
// rank1[i] = #{j<i : top1_j == top1_i}
// rank2[i] = #{j<i : top2_j == top2_i} + total_count(top1 == top2_i)
__global__ void __launch_bounds__(1024) k_ranks_scatter(
    const int* __restrict__ top1, const int* __restrict__ top2,
    const float* __restrict__ w1, const float* __restrict__ w2,
    int s, int capacity, float* __restrict__ out, size_t mask_off) {
    __shared__ unsigned short lr1[8192];
    __shared__ unsigned short lr2[8192];
    __shared__ int hist1[16][NEXPERTS];
    __shared__ int hist2[16][NEXPERTS];
    __shared__ int off1[16][NEXPERTS];
    __shared__ int off2[16][NEXPERTS];

    int tid = threadIdx.x;
    int w = tid >> 6;          // wave id: chunk owner
    int lane = tid & 63;       // lane == expert id in pass 1
    int chunk = (s + 15) >> 4; // 512 for s=8192
    int beg = w * chunk;
    int end = min(beg + chunk, s);

    // pass 1: per-chunk ordered local ranks (lane e counts expert e)
    int cnt1 = 0, cnt2 = 0;
    for (int base = beg; base < end; base += 64) {
        int n = min(64, end - base);
        int t1 = 0, t2 = 0;
        if (lane < n) { t1 = top1[base + lane]; t2 = top2[base + lane]; }
        for (int k = 0; k < n; ++k) {
            int i1 = __shfl(t1, k, 64);
            int i2 = __shfl(t2, k, 64);
            if (lane == i1) lr1[base + k] = (unsigned short)cnt1;
            cnt1 += (lane == i1) ? 1 : 0;
            if (lane == i2) lr2[base + k] = (unsigned short)cnt2;
            cnt2 += (lane == i2) ? 1 : 0;
        }
    }
    hist1[w][lane] = cnt1;
    hist2[w][lane] = cnt2;
    __syncthreads();

    // pass 2: exclusive scan of chunk histograms per expert (+ total top1)
    {
        int o1 = 0, o2 = 0, tot1 = 0;
        #pragma unroll
        for (int k = 0; k < 16; ++k) {
            int h1 = hist1[k][lane], h2 = hist2[k][lane];
            if (k < w) { o1 += h1; o2 += h2; }
            tot1 += h1;
        }
        off1[w][lane] = o1;
        off2[w][lane] = tot1 + o2;  // rank2 offset includes full top1 count
    }
    __syncthreads();

    // pass 3: scatter nonzeros into the pre-zeroed dense output
    for (int i = tid; i < s; i += 1024) {
        int c = i / chunk;
        int e1 = top1[i], e2 = top2[i];
        int r1 = (int)lr1[i] + off1[c][e1];
        int r2 = (int)lr2[i] + off2[c][e2];
        size_t row = (size_t)i * NEXPERTS * capacity;
        if (r1 < capacity) {
            float p1 = w1[i];
            size_t o = row + (size_t)e1 * capacity + r1;
            out[o] = p1;
            out[mask_off + o] = (p1 != 0.0f) ? 1.0f : 0.0f;
        }
        if (r2 < capacity) {
            float p2 = w2[i];
            size_t o = row + (size_t)e2 * capacity + r2;
            out[o] = p2;
            out[mask_off + o] = (p2 != 0.0f) ? 1.0f : 0.0f;
        }
    }
}

extern "C" void kernel_launch(void* const* d_in, const int* in_sizes, int n_in,
                              void* d_out, int out_size, void* d_ws, size_t ws_size,
                              hipStream_t stream) {
    const float* in = (const float*)d_in[0];
    int s = in_sizes[0] / NEXPERTS;          // 8192

    // capacity = max(floor(2.0*s/e) rounded up to even, 4)
    int cap = (int)(2.0 * s / NEXPERTS);
    cap += cap % 2;
    if (cap < 4) cap = 4;                    // = 256 here

    int*   top1  = (int*)d_ws;
    int*   top2  = top1 + s;
    float* w1    = (float*)(top2 + s);
    float* w2    = w1 + s;

    float* out = (float*)d_out;
    size_t mask_off = (size_t)s * NEXPERTS * cap;   // second output (mask)

    // zero the whole output (both tensors) via the runtime fill path
    hipMemsetAsync(d_out, 0, (size_t)out_size * sizeof(float), stream);

    int tokensPerBlock = 4;  // 4 waves of 64
    int b1 = (s + tokensPerBlock - 1) / tokensPerBlock;
    k_softmax_top2<<<b1, 256, 0, stream>>>(in, s, top1, top2, w1, w2);
    k_ranks_scatter<<<1, 1024, 0, stream>>>(top1, top2, w1, w2, s, cap, out, mask_off);
}